// Round 6
// baseline (2200.744 us; speedup 1.0000x reference)
//
#include <hip/hip_runtime.h>

// ---------------------------------------------------------------------------
// Bidirectional Mamba block, MI355X. Round 5: R4's reference-faithful pipeline
// with the CORRECT dtypes: all inputs and the output are FP32 (the reference's
// setup_inputs builds jnp.float32 arrays; prior rounds misread them as bf16 ->
// NaN from mantissa bits decoding as bf16 NaN patterns).
// Backward branch computed entirely in flipped coordinates (like jnp.flip),
// un-flipped only at the final sum. One kernel per reference op. Per-b slabs.
// Shapes: B=4, C=64, D=128, L=4096 (l = h*256 + w*16 + t), N=16, R=8.
// ---------------------------------------------------------------------------

#define NL 4096

__device__ __forceinline__ float siluf_(float x) { return x / (1.f + __expf(-x)); }
__device__ __forceinline__ float softplusf_(float x) {
  return (x > 20.f) ? x : log1pf(__expf(x));
}

// Per-b slab offsets (fp32 elements)
#define OXZ  0u          // xz   [256][4096]
#define OUCF 1048576u    // ucf  [128][4096]
#define OUCB 1572864u    // ucb  [128][4096]  (flipped coords)
#define OXDF 2097152u    // xdf  [40][4096]
#define OXDB 2260992u    // xdb  [40][4096]   (flipped coords)
#define ODLF 2424832u    // dlf  [128][4096]
#define ODLB 2949120u    // dlb  [128][4096]  (flipped coords)
#define OYF  3473408u    // yf   [128][4096]
#define OYB  3997696u    // yb   [128][4096]  (flipped coords)
#define OO   4521984u    // o    [128][4096]  gated sum
#define OO2  5046272u    // o2   [4096][64]   == x_recon NCDHW (byte identity)
#define OX4  5308416u    // x4   [64][4096]   conv3d + residual
#define PER_B 5570560u

// 1. xz[e,l] = sum_c in_proj_w[e,c] * x[b,c,t(l),h(l),w(l)]
__global__ void kxz(const float* __restrict__ x, const float* __restrict__ wip,
                    float* __restrict__ ws, int b0) {
  int bi = blockIdx.y, gb = b0 + bi;
  float* s = ws + (size_t)bi * PER_B;
  int l = blockIdx.x, e = threadIdx.x;
  int t = l & 15, h = l >> 8, w = (l >> 4) & 15;
  size_t xb = (size_t)gb * 64 * NL + t * 256 + h * 16 + w;
  float acc = 0.f;
  for (int c = 0; c < 64; ++c)
    acc = fmaf(wip[e * 64 + c], x[xb + (size_t)c * NL], acc);
  s[OXZ + (size_t)e * NL + l] = acc;
}

// 2. causal dwconv + silu. fwd on xz rows 0..127; bwd on flipped xz.
__global__ void kconv(const float* __restrict__ cwf, const float* __restrict__ cbf,
                      const float* __restrict__ cwb, const float* __restrict__ cbb,
                      float* __restrict__ ws) {
  int bi = blockIdx.y;
  float* s = ws + (size_t)bi * PER_B;
  int idx = blockIdx.x * 256 + threadIdx.x;  // 128*4096
  int d = idx >> 12, l = idx & 4095;
  const float* xz = s + OXZ + (size_t)d * NL;
  float af = cbf[d], ab = cbb[d];
#pragma unroll
  for (int k = 0; k < 4; ++k) {
    int j = l - 3 + k;
    if (j >= 0) {
      af = fmaf(cwf[d * 4 + k], xz[j], af);
      ab = fmaf(cwb[d * 4 + k], xz[NL - 1 - j], ab);  // x_b[j] = xz[L-1-j]
    }
  }
  s[OUCF + (size_t)d * NL + l] = siluf_(af);
  s[OUCB + (size_t)d * NL + l] = siluf_(ab);
}

// 3. x_dbl[e,l] = sum_d xproj[e,d] * uc[d,l]  (e<40, both branches)
__global__ void kxdbl(const float* __restrict__ xpf, const float* __restrict__ xpb,
                      float* __restrict__ ws) {
  int bi = blockIdx.y;
  float* s = ws + (size_t)bi * PER_B;
  int idx = blockIdx.x * 256 + threadIdx.x;  // 40*4096
  int e = idx >> 12, l = idx & 4095;
  float af = 0.f, ab = 0.f;
  for (int d = 0; d < 128; ++d) {
    af = fmaf(xpf[e * 128 + d], s[OUCF + (size_t)d * NL + l], af);
    ab = fmaf(xpb[e * 128 + d], s[OUCB + (size_t)d * NL + l], ab);
  }
  s[OXDF + (size_t)e * NL + l] = af;
  s[OXDB + (size_t)e * NL + l] = ab;
}

// 4. delta[d,l] = softplus(dtproj_b[d] + sum_r dtproj_w[d,r]*dt[r,l])
__global__ void kdelta(const float* __restrict__ dtwf, const float* __restrict__ dtbf,
                       const float* __restrict__ dtwb, const float* __restrict__ dtbb,
                       float* __restrict__ ws) {
  int bi = blockIdx.y;
  float* s = ws + (size_t)bi * PER_B;
  int idx = blockIdx.x * 256 + threadIdx.x;  // 128*4096
  int d = idx >> 12, l = idx & 4095;
  float af = dtbf[d], ab = dtbb[d];
#pragma unroll
  for (int r = 0; r < 8; ++r) {
    af = fmaf(dtwf[d * 8 + r], s[OXDF + (size_t)r * NL + l], af);
    ab = fmaf(dtwb[d * 8 + r], s[OXDB + (size_t)r * NL + l], ab);
  }
  s[ODLF + (size_t)d * NL + l] = softplusf_(af);
  s[ODLB + (size_t)d * NL + l] = softplusf_(ab);
}

// 5. selective scan, ascending l for BOTH branches (bwd is in flipped coords).
// 1 wave/block; 4 d-rows x 16 n-lanes. y[d,l] = sum_n h*C[n,l] + u*D.
__global__ __launch_bounds__(64) void kscan(
    const float* __restrict__ Alf, const float* __restrict__ Df,
    const float* __restrict__ Alb, const float* __restrict__ Db,
    float* __restrict__ ws) {
  int bi = blockIdx.y;
  float* s = ws + (size_t)bi * PER_B;
  int dir = blockIdx.x >> 5, dblk = blockIdx.x & 31;
  int n = threadIdx.x & 15, g = threadIdx.x >> 4;
  int d = dblk * 4 + g;
  const float* uc = s + (dir ? OUCB : OUCF) + (size_t)d * NL;
  const float* dl = s + (dir ? ODLB : ODLF) + (size_t)d * NL;
  const float* Bm = s + (dir ? OXDB : OXDF) + (size_t)(8 + n) * NL;
  const float* Cm = s + (dir ? OXDB : OXDF) + (size_t)(24 + n) * NL;
  float* y = s + (dir ? OYB : OYF) + (size_t)d * NL;
  float A = -__expf((dir ? Alb : Alf)[d * 16 + n]);
  float Dv = (dir ? Db : Df)[d];
  float h = 0.f;
#pragma unroll 4
  for (int l = 0; l < NL; ++l) {
    float dv = dl[l], uv = uc[l];
    float dA = __expf(dv * A);
    h = fmaf(dA, h, dv * Bm[l] * uv);
    float p = h * Cm[l];
    p += __shfl_xor(p, 1, 16);
    p += __shfl_xor(p, 2, 16);
    p += __shfl_xor(p, 4, 16);
    p += __shfl_xor(p, 8, 16);
    if (n == 0) y[l] = fmaf(uv, Dv, p);
  }
}

// 6. o[d,l] = (yf[d,l] + yb[d,L-1-l]) * silu(z[l])   (un-flip bwd here)
__global__ void kgate(float* __restrict__ ws) {
  int bi = blockIdx.y;
  float* s = ws + (size_t)bi * PER_B;
  int idx = blockIdx.x * 256 + threadIdx.x;  // 128*4096
  int d = idx >> 12, l = idx & 4095;
  float gz = siluf_(s[OXZ + (size_t)(128 + d) * NL + l]);
  float v = s[OYF + (size_t)d * NL + l] + s[OYB + (size_t)d * NL + (NL - 1 - l)];
  s[OO + (size_t)d * NL + l] = v * gz;
}

// 7. o2[l,c] = sum_d out_proj_w[c,d] * o[d,l]   (o2 bytes == x_recon NCDHW)
__global__ void kout(const float* __restrict__ wout, float* __restrict__ ws) {
  int bi = blockIdx.y;
  float* s = ws + (size_t)bi * PER_B;
  int idx = blockIdx.x * 256 + threadIdx.x;  // 4096*64
  int l = idx >> 6, c = idx & 63;
  float acc = 0.f;
  for (int d = 0; d < 128; ++d)
    acc = fmaf(wout[c * 128 + d], s[OO + (size_t)d * NL + l], acc);
  s[OO2 + (size_t)l * 64 + c] = acc;
}

// 8. x4 = conv3d(x_recon, proj_w, pad=1) + proj_b + residual x
__global__ void kconv3(const float* __restrict__ pw, const float* __restrict__ pb,
                       const float* __restrict__ xin, float* __restrict__ ws, int b0) {
  int bi = blockIdx.y, gb = b0 + bi;
  float* s = ws + (size_t)bi * PER_B;
  int idx = blockIdx.x * 256 + threadIdx.x;  // 64*4096
  int co = idx >> 12, rem = idx & 4095;
  int t = rem >> 8, h = (rem >> 4) & 15, w = rem & 15;
  const float* xr = s + OO2;  // reinterpret (L,C) bytes as (C,T,H,W)
  float acc = pb[co];
  for (int ci = 0; ci < 64; ++ci) {
    const float* wb = pw + (co * 64 + ci) * 27;
    const float* xc = xr + (size_t)ci * NL;
#pragma unroll
    for (int kt = 0; kt < 3; ++kt) {
      int ts = t + kt - 1;
      if (ts < 0 || ts > 15) continue;
#pragma unroll
      for (int kh = 0; kh < 3; ++kh) {
        int hs = h + kh - 1;
        if (hs < 0 || hs > 15) continue;
#pragma unroll
        for (int kw = 0; kw < 3; ++kw) {
          int wv = w + kw - 1;
          if (wv < 0 || wv > 15) continue;
          acc = fmaf(wb[kt * 9 + kh * 3 + kw], xc[ts * 256 + hs * 16 + wv], acc);
        }
      }
    }
  }
  s[OX4 + (size_t)co * NL + rem] = acc + xin[(size_t)(gb * 64 + co) * NL + rem];
}

// 9. out = 1x1x1 channel mix + norm_b -> fp32 output
__global__ void knorm(const float* __restrict__ nw, const float* __restrict__ nb,
                      float* __restrict__ out, float* __restrict__ ws, int b0) {
  int bi = blockIdx.y, gb = b0 + bi;
  float* s = ws + (size_t)bi * PER_B;
  int idx = blockIdx.x * 256 + threadIdx.x;  // 64*4096
  int co = idx >> 12, p = idx & 4095;
  float acc = nb[co];
  for (int ci = 0; ci < 64; ++ci)
    acc = fmaf(nw[co * 64 + ci], s[OX4 + (size_t)ci * NL + p], acc);
  out[(size_t)(gb * 64 + co) * NL + p] = acc;
}

// ---------------------------------------------------------------------------
extern "C" void kernel_launch(void* const* d_in, const int* in_sizes, int n_in,
                              void* d_out, int out_size, void* d_ws, size_t ws_size,
                              hipStream_t stream) {
  const float* x    = (const float*)d_in[0];
  const float* wip  = (const float*)d_in[1];
  const float* cwf  = (const float*)d_in[2];
  const float* cbf  = (const float*)d_in[3];
  const float* xpf  = (const float*)d_in[4];
  const float* dtwf = (const float*)d_in[5];
  const float* dtbf = (const float*)d_in[6];
  const float* Alf  = (const float*)d_in[7];
  const float* Df   = (const float*)d_in[8];
  const float* cwb  = (const float*)d_in[9];
  const float* cbb  = (const float*)d_in[10];
  const float* xpb  = (const float*)d_in[11];
  const float* dtwb = (const float*)d_in[12];
  const float* dtbb = (const float*)d_in[13];
  const float* Alb  = (const float*)d_in[14];
  const float* Db   = (const float*)d_in[15];
  const float* wout = (const float*)d_in[16];
  const float* pw   = (const float*)d_in[17];
  const float* pb   = (const float*)d_in[18];
  const float* nw   = (const float*)d_in[19];
  const float* nb   = (const float*)d_in[20];

  const size_t PER_B_BYTES = (size_t)PER_B * 4;  // 22,282,240 per batch slab
  int bcnt;
  if (ws_size >= 4 * PER_B_BYTES) bcnt = 4;
  else if (ws_size >= PER_B_BYTES) bcnt = 1;
  else return;  // diagnostic: d_out stays 0 -> absmax == max|ref| (finite)
  int passes = 4 / bcnt;

  float* ws = (float*)d_ws;
  for (int p = 0; p < passes; ++p) {
    int b0 = p * bcnt;
    kxz   <<<dim3(4096, bcnt), 256, 0, stream>>>(x, wip, ws, b0);
    kconv <<<dim3(2048, bcnt), 256, 0, stream>>>(cwf, cbf, cwb, cbb, ws);
    kxdbl <<<dim3(640, bcnt), 256, 0, stream>>>(xpf, xpb, ws);
    kdelta<<<dim3(2048, bcnt), 256, 0, stream>>>(dtwf, dtbf, dtwb, dtbb, ws);
    kscan <<<dim3(64, bcnt), 64, 0, stream>>>(Alf, Df, Alb, Db, ws);
    kgate <<<dim3(2048, bcnt), 256, 0, stream>>>(ws);
    kout  <<<dim3(1024, bcnt), 256, 0, stream>>>(wout, ws);
    kconv3<<<dim3(1024, bcnt), 256, 0, stream>>>(pw, pb, x, ws, b0);
    knorm <<<dim3(1024, bcnt), 256, 0, stream>>>(nw, nb, (float*)d_out, ws, b0);
  }
}

// Round 7
// 1217.551 us; speedup vs baseline: 1.8075x; 1.8075x over previous
//
#include <hip/hip_runtime.h>

// ---------------------------------------------------------------------------
// Bidirectional Mamba block, MI355X. Round 6: chunked parallel selective scan
// (64 chunks x 64 steps: parallel chunk-local scan -> 64-step carry combine ->
// parallel seeded re-scan). Replaces the 1294us latency-bound serial kscan.
// All other kernels unchanged from the passing R5 baseline.
// Shapes: B=4, C=64, D=128, L=4096 (l = h*256 + w*16 + t), N=16, R=8.
// ---------------------------------------------------------------------------

#define NL 4096

__device__ __forceinline__ float siluf_(float x) { return x / (1.f + __expf(-x)); }
__device__ __forceinline__ float softplusf_(float x) {
  return (x > 20.f) ? x : log1pf(__expf(x));
}

// Per-b slab offsets (fp32 elements)
#define OXZ  0u          // xz   [256][4096]
#define OUCF 1048576u    // ucf  [128][4096]
#define OUCB 1572864u    // ucb  [128][4096]  (flipped coords)
#define OXDF 2097152u    // xdf  [40][4096]
#define OXDB 2260992u    // xdb  [40][4096]   (flipped coords)
#define ODLF 2424832u    // dlf  [128][4096]
#define ODLB 2949120u    // dlb  [128][4096]  (flipped coords)
#define OYF  3473408u    // yf   [128][4096]
#define OYB  3997696u    // yb   [128][4096]  (flipped coords)
#define OO   4521984u    // o    [128][4096]  gated sum; scan phases borrow it:
                         //   [OO, OO+262144)         P (chunk decay products)
                         //   [OO+262144, OO+524288)  S -> h_in carries
#define OO2  5046272u    // o2   [4096][64]   == x_recon NCDHW (byte identity)
#define OX4  5308416u    // x4   [64][4096]   conv3d + residual
#define PER_B 5570560u

#define NCH 64   // chunks
#define CL  64   // chunk length

// 1. xz[e,l] = sum_c in_proj_w[e,c] * x[b,c,t(l),h(l),w(l)]
__global__ void kxz(const float* __restrict__ x, const float* __restrict__ wip,
                    float* __restrict__ ws, int b0) {
  int bi = blockIdx.y, gb = b0 + bi;
  float* s = ws + (size_t)bi * PER_B;
  int l = blockIdx.x, e = threadIdx.x;
  int t = l & 15, h = l >> 8, w = (l >> 4) & 15;
  size_t xb = (size_t)gb * 64 * NL + t * 256 + h * 16 + w;
  float acc = 0.f;
  for (int c = 0; c < 64; ++c)
    acc = fmaf(wip[e * 64 + c], x[xb + (size_t)c * NL], acc);
  s[OXZ + (size_t)e * NL + l] = acc;
}

// 2. causal dwconv + silu. fwd on xz rows 0..127; bwd on flipped xz.
__global__ void kconv(const float* __restrict__ cwf, const float* __restrict__ cbf,
                      const float* __restrict__ cwb, const float* __restrict__ cbb,
                      float* __restrict__ ws) {
  int bi = blockIdx.y;
  float* s = ws + (size_t)bi * PER_B;
  int idx = blockIdx.x * 256 + threadIdx.x;  // 128*4096
  int d = idx >> 12, l = idx & 4095;
  const float* xz = s + OXZ + (size_t)d * NL;
  float af = cbf[d], ab = cbb[d];
#pragma unroll
  for (int k = 0; k < 4; ++k) {
    int j = l - 3 + k;
    if (j >= 0) {
      af = fmaf(cwf[d * 4 + k], xz[j], af);
      ab = fmaf(cwb[d * 4 + k], xz[NL - 1 - j], ab);  // x_b[j] = xz[L-1-j]
    }
  }
  s[OUCF + (size_t)d * NL + l] = siluf_(af);
  s[OUCB + (size_t)d * NL + l] = siluf_(ab);
}

// 3. x_dbl[e,l] = sum_d xproj[e,d] * uc[d,l]  (e<40, both branches)
__global__ void kxdbl(const float* __restrict__ xpf, const float* __restrict__ xpb,
                      float* __restrict__ ws) {
  int bi = blockIdx.y;
  float* s = ws + (size_t)bi * PER_B;
  int idx = blockIdx.x * 256 + threadIdx.x;  // 40*4096
  int e = idx >> 12, l = idx & 4095;
  float af = 0.f, ab = 0.f;
  for (int d = 0; d < 128; ++d) {
    af = fmaf(xpf[e * 128 + d], s[OUCF + (size_t)d * NL + l], af);
    ab = fmaf(xpb[e * 128 + d], s[OUCB + (size_t)d * NL + l], ab);
  }
  s[OXDF + (size_t)e * NL + l] = af;
  s[OXDB + (size_t)e * NL + l] = ab;
}

// 4. delta[d,l] = softplus(dtproj_b[d] + sum_r dtproj_w[d,r]*dt[r,l])
__global__ void kdelta(const float* __restrict__ dtwf, const float* __restrict__ dtbf,
                       const float* __restrict__ dtwb, const float* __restrict__ dtbb,
                       float* __restrict__ ws) {
  int bi = blockIdx.y;
  float* s = ws + (size_t)bi * PER_B;
  int idx = blockIdx.x * 256 + threadIdx.x;  // 128*4096
  int d = idx >> 12, l = idx & 4095;
  float af = dtbf[d], ab = dtbb[d];
#pragma unroll
  for (int r = 0; r < 8; ++r) {
    af = fmaf(dtwf[d * 8 + r], s[OXDF + (size_t)r * NL + l], af);
    ab = fmaf(dtwb[d * 8 + r], s[OXDB + (size_t)r * NL + l], ab);
  }
  s[ODLF + (size_t)d * NL + l] = softplusf_(af);
  s[ODLB + (size_t)d * NL + l] = softplusf_(ab);
}

// 5a. Phase A: per-chunk local scan. P = prod(dA), S = chunk scan (h0=0).
// blockIdx.x = chunk*64 + dir*32 + dblk; 64 thr = 4 d-rows x 16 n.
__global__ __launch_bounds__(64) void kscanA(
    const float* __restrict__ Alf, const float* __restrict__ Alb,
    float* __restrict__ ws) {
  int bi = blockIdx.y;
  float* s = ws + (size_t)bi * PER_B;
  int xid = blockIdx.x;
  int chunk = xid >> 6, dir = (xid >> 5) & 1, dblk = xid & 31;
  int n = threadIdx.x & 15, g = threadIdx.x >> 4;
  int d = dblk * 4 + g;
  const float* uc = s + (dir ? OUCB : OUCF) + (size_t)d * NL;
  const float* dl = s + (dir ? ODLB : ODLF) + (size_t)d * NL;
  const float* Bm = s + (dir ? OXDB : OXDF) + (size_t)(8 + n) * NL;
  float A = -__expf((dir ? Alb : Alf)[d * 16 + n]);
  int l0 = chunk * CL;
  float P = 1.f, S = 0.f;
#pragma unroll 4
  for (int i = 0; i < CL; ++i) {
    int l = l0 + i;
    float dv = dl[l];
    float dA = __expf(dv * A);
    S = fmaf(dA, S, dv * Bm[l] * uc[l]);
    P *= dA;
  }
  size_t cidx = (((size_t)dir * 128 + d) * 16 + n) * NCH + chunk;
  s[OO + cidx] = P;
  s[OO + 262144u + cidx] = S;
}

// 5b. Phase B: carry combine across chunks. S[c] <- h_in (state at chunk start).
// blockIdx.x = dir*32 + dblk; 64 thr = 4 d x 16 n.
__global__ __launch_bounds__(64) void kscanB(float* __restrict__ ws) {
  int bi = blockIdx.y;
  float* s = ws + (size_t)bi * PER_B;
  int dir = blockIdx.x >> 5, dblk = blockIdx.x & 31;
  int n = threadIdx.x & 15, g = threadIdx.x >> 4;
  int d = dblk * 4 + g;
  float* P = s + OO + (((size_t)dir * 128 + d) * 16 + n) * NCH;
  float* S = P + 262144u;
  float carry = 0.f;
#pragma unroll 4
  for (int c = 0; c < NCH; ++c) {
    float pv = P[c], sv = S[c];
    S[c] = carry;
    carry = fmaf(pv, carry, sv);
  }
}

// 5c. Phase C: seeded re-scan per chunk; emit y with 16-lane n-reduction.
__global__ __launch_bounds__(64) void kscanC(
    const float* __restrict__ Alf, const float* __restrict__ Df,
    const float* __restrict__ Alb, const float* __restrict__ Db,
    float* __restrict__ ws) {
  int bi = blockIdx.y;
  float* s = ws + (size_t)bi * PER_B;
  int xid = blockIdx.x;
  int chunk = xid >> 6, dir = (xid >> 5) & 1, dblk = xid & 31;
  int n = threadIdx.x & 15, g = threadIdx.x >> 4;
  int d = dblk * 4 + g;
  const float* uc = s + (dir ? OUCB : OUCF) + (size_t)d * NL;
  const float* dl = s + (dir ? ODLB : ODLF) + (size_t)d * NL;
  const float* Bm = s + (dir ? OXDB : OXDF) + (size_t)(8 + n) * NL;
  const float* Cm = s + (dir ? OXDB : OXDF) + (size_t)(24 + n) * NL;
  float* y = s + (dir ? OYB : OYF) + (size_t)d * NL;
  float A = -__expf((dir ? Alb : Alf)[d * 16 + n]);
  float Dv = (dir ? Db : Df)[d];
  size_t cidx = (((size_t)dir * 128 + d) * 16 + n) * NCH + chunk;
  float h = s[OO + 262144u + cidx];  // h_in at chunk start
  int l0 = chunk * CL;
#pragma unroll 2
  for (int i = 0; i < CL; ++i) {
    int l = l0 + i;
    float dv = dl[l], uv = uc[l];
    float dA = __expf(dv * A);
    h = fmaf(dA, h, dv * Bm[l] * uv);
    float p = h * Cm[l];
    p += __shfl_xor(p, 1, 16);
    p += __shfl_xor(p, 2, 16);
    p += __shfl_xor(p, 4, 16);
    p += __shfl_xor(p, 8, 16);
    if (n == 0) y[l] = fmaf(uv, Dv, p);
  }
}

// 6. o[d,l] = (yf[d,l] + yb[d,L-1-l]) * silu(z[l])   (un-flip bwd here)
__global__ void kgate(float* __restrict__ ws) {
  int bi = blockIdx.y;
  float* s = ws + (size_t)bi * PER_B;
  int idx = blockIdx.x * 256 + threadIdx.x;  // 128*4096
  int d = idx >> 12, l = idx & 4095;
  float gz = siluf_(s[OXZ + (size_t)(128 + d) * NL + l]);
  float v = s[OYF + (size_t)d * NL + l] + s[OYB + (size_t)d * NL + (NL - 1 - l)];
  s[OO + (size_t)d * NL + l] = v * gz;
}

// 7. o2[l,c] = sum_d out_proj_w[c,d] * o[d,l]   (o2 bytes == x_recon NCDHW)
__global__ void kout(const float* __restrict__ wout, float* __restrict__ ws) {
  int bi = blockIdx.y;
  float* s = ws + (size_t)bi * PER_B;
  int idx = blockIdx.x * 256 + threadIdx.x;  // 4096*64
  int l = idx >> 6, c = idx & 63;
  float acc = 0.f;
  for (int d = 0; d < 128; ++d)
    acc = fmaf(wout[c * 128 + d], s[OO + (size_t)d * NL + l], acc);
  s[OO2 + (size_t)l * 64 + c] = acc;
}

// 8. x4 = conv3d(x_recon, proj_w, pad=1) + proj_b + residual x
__global__ void kconv3(const float* __restrict__ pw, const float* __restrict__ pb,
                       const float* __restrict__ xin, float* __restrict__ ws, int b0) {
  int bi = blockIdx.y, gb = b0 + bi;
  float* s = ws + (size_t)bi * PER_B;
  int idx = blockIdx.x * 256 + threadIdx.x;  // 64*4096
  int co = idx >> 12, rem = idx & 4095;
  int t = rem >> 8, h = (rem >> 4) & 15, w = rem & 15;
  const float* xr = s + OO2;  // reinterpret (L,C) bytes as (C,T,H,W)
  float acc = pb[co];
  for (int ci = 0; ci < 64; ++ci) {
    const float* wb = pw + (co * 64 + ci) * 27;
    const float* xc = xr + (size_t)ci * NL;
#pragma unroll
    for (int kt = 0; kt < 3; ++kt) {
      int ts = t + kt - 1;
      if (ts < 0 || ts > 15) continue;
#pragma unroll
      for (int kh = 0; kh < 3; ++kh) {
        int hs = h + kh - 1;
        if (hs < 0 || hs > 15) continue;
#pragma unroll
        for (int kw = 0; kw < 3; ++kw) {
          int wv = w + kw - 1;
          if (wv < 0 || wv > 15) continue;
          acc = fmaf(wb[kt * 9 + kh * 3 + kw], xc[ts * 256 + hs * 16 + wv], acc);
        }
      }
    }
  }
  s[OX4 + (size_t)co * NL + rem] = acc + xin[(size_t)(gb * 64 + co) * NL + rem];
}

// 9. out = 1x1x1 channel mix + norm_b -> fp32 output
__global__ void knorm(const float* __restrict__ nw, const float* __restrict__ nb,
                      float* __restrict__ out, float* __restrict__ ws, int b0) {
  int bi = blockIdx.y, gb = b0 + bi;
  float* s = ws + (size_t)bi * PER_B;
  int idx = blockIdx.x * 256 + threadIdx.x;  // 64*4096
  int co = idx >> 12, p = idx & 4095;
  float acc = nb[co];
  for (int ci = 0; ci < 64; ++ci)
    acc = fmaf(nw[co * 64 + ci], s[OX4 + (size_t)ci * NL + p], acc);
  out[(size_t)(gb * 64 + co) * NL + p] = acc;
}

// ---------------------------------------------------------------------------
extern "C" void kernel_launch(void* const* d_in, const int* in_sizes, int n_in,
                              void* d_out, int out_size, void* d_ws, size_t ws_size,
                              hipStream_t stream) {
  const float* x    = (const float*)d_in[0];
  const float* wip  = (const float*)d_in[1];
  const float* cwf  = (const float*)d_in[2];
  const float* cbf  = (const float*)d_in[3];
  const float* xpf  = (const float*)d_in[4];
  const float* dtwf = (const float*)d_in[5];
  const float* dtbf = (const float*)d_in[6];
  const float* Alf  = (const float*)d_in[7];
  const float* Df   = (const float*)d_in[8];
  const float* cwb  = (const float*)d_in[9];
  const float* cbb  = (const float*)d_in[10];
  const float* xpb  = (const float*)d_in[11];
  const float* dtwb = (const float*)d_in[12];
  const float* dtbb = (const float*)d_in[13];
  const float* Alb  = (const float*)d_in[14];
  const float* Db   = (const float*)d_in[15];
  const float* wout = (const float*)d_in[16];
  const float* pw   = (const float*)d_in[17];
  const float* pb   = (const float*)d_in[18];
  const float* nw   = (const float*)d_in[19];
  const float* nb   = (const float*)d_in[20];

  const size_t PER_B_BYTES = (size_t)PER_B * 4;  // 22,282,240 per batch slab
  int bcnt;
  if (ws_size >= 4 * PER_B_BYTES) bcnt = 4;
  else if (ws_size >= PER_B_BYTES) bcnt = 1;
  else return;
  int passes = 4 / bcnt;

  float* ws = (float*)d_ws;
  for (int p = 0; p < passes; ++p) {
    int b0 = p * bcnt;
    kxz   <<<dim3(4096, bcnt), 256, 0, stream>>>(x, wip, ws, b0);
    kconv <<<dim3(2048, bcnt), 256, 0, stream>>>(cwf, cbf, cwb, cbb, ws);
    kxdbl <<<dim3(640, bcnt), 256, 0, stream>>>(xpf, xpb, ws);
    kdelta<<<dim3(2048, bcnt), 256, 0, stream>>>(dtwf, dtbf, dtwb, dtbb, ws);
    kscanA<<<dim3(4096, bcnt), 64, 0, stream>>>(Alf, Alb, ws);
    kscanB<<<dim3(64, bcnt), 64, 0, stream>>>(ws);
    kscanC<<<dim3(4096, bcnt), 64, 0, stream>>>(Alf, Df, Alb, Db, ws);
    kgate <<<dim3(2048, bcnt), 256, 0, stream>>>(ws);
    kout  <<<dim3(1024, bcnt), 256, 0, stream>>>(wout, ws);
    kconv3<<<dim3(1024, bcnt), 256, 0, stream>>>(pw, pb, x, ws, b0);
    knorm <<<dim3(1024, bcnt), 256, 0, stream>>>(nw, nb, (float*)d_out, ws, b0);
  }
}

// Round 8
// 789.975 us; speedup vs baseline: 2.7858x; 1.5413x over previous
//
#include <hip/hip_runtime.h>

// ---------------------------------------------------------------------------
// Bidirectional Mamba block, MI355X. Round 7: LDS-tiled conv3d (kconv3).
// R6's kconv3 had zero reuse (1728 L2 loads/thread, 30% VALU, 565us).
// New kconv3: block=(bi,t,h), stages 64ci x 3t x 3h x 18w halo into LDS
// (zero-padded -> branchless inner loop), each thread computes (co, 4 w).
// All other kernels unchanged from the passing R6 kernel.
// Shapes: B=4, C=64, D=128, L=4096 (l = h*256 + w*16 + t), N=16, R=8.
// ---------------------------------------------------------------------------

#define NL 4096

__device__ __forceinline__ float siluf_(float x) { return x / (1.f + __expf(-x)); }
__device__ __forceinline__ float softplusf_(float x) {
  return (x > 20.f) ? x : log1pf(__expf(x));
}

// Per-b slab offsets (fp32 elements)
#define OXZ  0u          // xz   [256][4096]
#define OUCF 1048576u    // ucf  [128][4096]
#define OUCB 1572864u    // ucb  [128][4096]  (flipped coords)
#define OXDF 2097152u    // xdf  [40][4096]
#define OXDB 2260992u    // xdb  [40][4096]   (flipped coords)
#define ODLF 2424832u    // dlf  [128][4096]
#define ODLB 2949120u    // dlb  [128][4096]  (flipped coords)
#define OYF  3473408u    // yf   [128][4096]
#define OYB  3997696u    // yb   [128][4096]  (flipped coords)
#define OO   4521984u    // o    [128][4096]  gated sum; scan phases borrow it:
                         //   [OO, OO+262144)         P (chunk decay products)
                         //   [OO+262144, OO+524288)  S -> h_in carries
#define OO2  5046272u    // o2   [4096][64]   == x_recon NCDHW (byte identity)
#define OX4  5308416u    // x4   [64][4096]   conv3d + residual
#define PER_B 5570560u

#define NCH 64   // scan chunks
#define CL  64   // chunk length

// 1. xz[e,l] = sum_c in_proj_w[e,c] * x[b,c,t(l),h(l),w(l)]
__global__ void kxz(const float* __restrict__ x, const float* __restrict__ wip,
                    float* __restrict__ ws, int b0) {
  int bi = blockIdx.y, gb = b0 + bi;
  float* s = ws + (size_t)bi * PER_B;
  int l = blockIdx.x, e = threadIdx.x;
  int t = l & 15, h = l >> 8, w = (l >> 4) & 15;
  size_t xb = (size_t)gb * 64 * NL + t * 256 + h * 16 + w;
  float acc = 0.f;
  for (int c = 0; c < 64; ++c)
    acc = fmaf(wip[e * 64 + c], x[xb + (size_t)c * NL], acc);
  s[OXZ + (size_t)e * NL + l] = acc;
}

// 2. causal dwconv + silu. fwd on xz rows 0..127; bwd on flipped xz.
__global__ void kconv(const float* __restrict__ cwf, const float* __restrict__ cbf,
                      const float* __restrict__ cwb, const float* __restrict__ cbb,
                      float* __restrict__ ws) {
  int bi = blockIdx.y;
  float* s = ws + (size_t)bi * PER_B;
  int idx = blockIdx.x * 256 + threadIdx.x;  // 128*4096
  int d = idx >> 12, l = idx & 4095;
  const float* xz = s + OXZ + (size_t)d * NL;
  float af = cbf[d], ab = cbb[d];
#pragma unroll
  for (int k = 0; k < 4; ++k) {
    int j = l - 3 + k;
    if (j >= 0) {
      af = fmaf(cwf[d * 4 + k], xz[j], af);
      ab = fmaf(cwb[d * 4 + k], xz[NL - 1 - j], ab);  // x_b[j] = xz[L-1-j]
    }
  }
  s[OUCF + (size_t)d * NL + l] = siluf_(af);
  s[OUCB + (size_t)d * NL + l] = siluf_(ab);
}

// 3. x_dbl[e,l] = sum_d xproj[e,d] * uc[d,l]  (e<40, both branches)
__global__ void kxdbl(const float* __restrict__ xpf, const float* __restrict__ xpb,
                      float* __restrict__ ws) {
  int bi = blockIdx.y;
  float* s = ws + (size_t)bi * PER_B;
  int idx = blockIdx.x * 256 + threadIdx.x;  // 40*4096
  int e = idx >> 12, l = idx & 4095;
  float af = 0.f, ab = 0.f;
  for (int d = 0; d < 128; ++d) {
    af = fmaf(xpf[e * 128 + d], s[OUCF + (size_t)d * NL + l], af);
    ab = fmaf(xpb[e * 128 + d], s[OUCB + (size_t)d * NL + l], ab);
  }
  s[OXDF + (size_t)e * NL + l] = af;
  s[OXDB + (size_t)e * NL + l] = ab;
}

// 4. delta[d,l] = softplus(dtproj_b[d] + sum_r dtproj_w[d,r]*dt[r,l])
__global__ void kdelta(const float* __restrict__ dtwf, const float* __restrict__ dtbf,
                       const float* __restrict__ dtwb, const float* __restrict__ dtbb,
                       float* __restrict__ ws) {
  int bi = blockIdx.y;
  float* s = ws + (size_t)bi * PER_B;
  int idx = blockIdx.x * 256 + threadIdx.x;  // 128*4096
  int d = idx >> 12, l = idx & 4095;
  float af = dtbf[d], ab = dtbb[d];
#pragma unroll
  for (int r = 0; r < 8; ++r) {
    af = fmaf(dtwf[d * 8 + r], s[OXDF + (size_t)r * NL + l], af);
    ab = fmaf(dtwb[d * 8 + r], s[OXDB + (size_t)r * NL + l], ab);
  }
  s[ODLF + (size_t)d * NL + l] = softplusf_(af);
  s[ODLB + (size_t)d * NL + l] = softplusf_(ab);
}

// 5a. Phase A: per-chunk local scan. P = prod(dA), S = chunk scan (h0=0).
__global__ __launch_bounds__(64) void kscanA(
    const float* __restrict__ Alf, const float* __restrict__ Alb,
    float* __restrict__ ws) {
  int bi = blockIdx.y;
  float* s = ws + (size_t)bi * PER_B;
  int xid = blockIdx.x;
  int chunk = xid >> 6, dir = (xid >> 5) & 1, dblk = xid & 31;
  int n = threadIdx.x & 15, g = threadIdx.x >> 4;
  int d = dblk * 4 + g;
  const float* uc = s + (dir ? OUCB : OUCF) + (size_t)d * NL;
  const float* dl = s + (dir ? ODLB : ODLF) + (size_t)d * NL;
  const float* Bm = s + (dir ? OXDB : OXDF) + (size_t)(8 + n) * NL;
  float A = -__expf((dir ? Alb : Alf)[d * 16 + n]);
  int l0 = chunk * CL;
  float P = 1.f, S = 0.f;
#pragma unroll 4
  for (int i = 0; i < CL; ++i) {
    int l = l0 + i;
    float dv = dl[l];
    float dA = __expf(dv * A);
    S = fmaf(dA, S, dv * Bm[l] * uc[l]);
    P *= dA;
  }
  size_t cidx = (((size_t)dir * 128 + d) * 16 + n) * NCH + chunk;
  s[OO + cidx] = P;
  s[OO + 262144u + cidx] = S;
}

// 5b. Phase B: carry combine across chunks. S[c] <- h_in (state at chunk start).
__global__ __launch_bounds__(64) void kscanB(float* __restrict__ ws) {
  int bi = blockIdx.y;
  float* s = ws + (size_t)bi * PER_B;
  int dir = blockIdx.x >> 5, dblk = blockIdx.x & 31;
  int n = threadIdx.x & 15, g = threadIdx.x >> 4;
  int d = dblk * 4 + g;
  float* P = s + OO + (((size_t)dir * 128 + d) * 16 + n) * NCH;
  float* S = P + 262144u;
  float carry = 0.f;
#pragma unroll 4
  for (int c = 0; c < NCH; ++c) {
    float pv = P[c], sv = S[c];
    S[c] = carry;
    carry = fmaf(pv, carry, sv);
  }
}

// 5c. Phase C: seeded re-scan per chunk; emit y with 16-lane n-reduction.
__global__ __launch_bounds__(64) void kscanC(
    const float* __restrict__ Alf, const float* __restrict__ Df,
    const float* __restrict__ Alb, const float* __restrict__ Db,
    float* __restrict__ ws) {
  int bi = blockIdx.y;
  float* s = ws + (size_t)bi * PER_B;
  int xid = blockIdx.x;
  int chunk = xid >> 6, dir = (xid >> 5) & 1, dblk = xid & 31;
  int n = threadIdx.x & 15, g = threadIdx.x >> 4;
  int d = dblk * 4 + g;
  const float* uc = s + (dir ? OUCB : OUCF) + (size_t)d * NL;
  const float* dl = s + (dir ? ODLB : ODLF) + (size_t)d * NL;
  const float* Bm = s + (dir ? OXDB : OXDF) + (size_t)(8 + n) * NL;
  const float* Cm = s + (dir ? OXDB : OXDF) + (size_t)(24 + n) * NL;
  float* y = s + (dir ? OYB : OYF) + (size_t)d * NL;
  float A = -__expf((dir ? Alb : Alf)[d * 16 + n]);
  float Dv = (dir ? Db : Df)[d];
  size_t cidx = (((size_t)dir * 128 + d) * 16 + n) * NCH + chunk;
  float h = s[OO + 262144u + cidx];  // h_in at chunk start
  int l0 = chunk * CL;
#pragma unroll 2
  for (int i = 0; i < CL; ++i) {
    int l = l0 + i;
    float dv = dl[l], uv = uc[l];
    float dA = __expf(dv * A);
    h = fmaf(dA, h, dv * Bm[l] * uv);
    float p = h * Cm[l];
    p += __shfl_xor(p, 1, 16);
    p += __shfl_xor(p, 2, 16);
    p += __shfl_xor(p, 4, 16);
    p += __shfl_xor(p, 8, 16);
    if (n == 0) y[l] = fmaf(uv, Dv, p);
  }
}

// 6. o[d,l] = (yf[d,l] + yb[d,L-1-l]) * silu(z[l])   (un-flip bwd here)
__global__ void kgate(float* __restrict__ ws) {
  int bi = blockIdx.y;
  float* s = ws + (size_t)bi * PER_B;
  int idx = blockIdx.x * 256 + threadIdx.x;  // 128*4096
  int d = idx >> 12, l = idx & 4095;
  float gz = siluf_(s[OXZ + (size_t)(128 + d) * NL + l]);
  float v = s[OYF + (size_t)d * NL + l] + s[OYB + (size_t)d * NL + (NL - 1 - l)];
  s[OO + (size_t)d * NL + l] = v * gz;
}

// 7. o2[l,c] = sum_d out_proj_w[c,d] * o[d,l]   (o2 bytes == x_recon NCDHW)
__global__ void kout(const float* __restrict__ wout, float* __restrict__ ws) {
  int bi = blockIdx.y;
  float* s = ws + (size_t)bi * PER_B;
  int idx = blockIdx.x * 256 + threadIdx.x;  // 4096*64
  int l = idx >> 6, c = idx & 63;
  float acc = 0.f;
  for (int d = 0; d < 128; ++d)
    acc = fmaf(wout[c * 128 + d], s[OO + (size_t)d * NL + l], acc);
  s[OO2 + (size_t)l * 64 + c] = acc;
}

// 8. x4 = conv3d(x_recon, proj_w, pad=1) + proj_b + residual x.
// LDS-tiled: block=(bi, t, h); Xs = 64ci x 3t x 3h x 18w zero-padded halo.
// Thread (co, wq): 4 outputs along w. Branchless inner loop over ci,kt,kh.
__global__ __launch_bounds__(256) void kconv3(
    const float* __restrict__ pw, const float* __restrict__ pb,
    const float* __restrict__ xin, float* __restrict__ ws, int b0) {
  int bi = blockIdx.y, gb = b0 + bi;
  float* s = ws + (size_t)bi * PER_B;
  int t = blockIdx.x >> 4, h = blockIdx.x & 15;
  int tid = threadIdx.x;
  const float* xr = s + OO2;  // (L,C) bytes == (C,T,H,W)
  __shared__ float Xs[64][3][3][18];  // 40.5 KB, ww = w+1 for w in -1..16
  for (int i = tid; i < 64 * 162; i += 256) {
    int ci = i / 162;
    int rem = i - ci * 162;
    int tt = rem / 54;
    int rem2 = rem - tt * 54;
    int hh = rem2 / 18;
    int ww = rem2 - hh * 18;
    int ts = t + tt - 1, hs = h + hh - 1, wv = ww - 1;
    float v = 0.f;
    if (ts >= 0 && ts < 16 && hs >= 0 && hs < 16 && wv >= 0 && wv < 16)
      v = xr[(size_t)ci * NL + ts * 256 + hs * 16 + wv];
    Xs[ci][tt][hh][ww] = v;
  }
  __syncthreads();
  int co = tid >> 2, wq = tid & 3;
  int w0 = wq * 4;
  float a0 = 0.f, a1 = 0.f, a2 = 0.f, a3 = 0.f;
  const float* wbase = pw + co * (64 * 27);
  for (int ci = 0; ci < 64; ++ci) {
#pragma unroll
    for (int kt = 0; kt < 3; ++kt) {
#pragma unroll
      for (int kh = 0; kh < 3; ++kh) {
        const float* xrow = &Xs[ci][kt][kh][w0];
        const float* wr = wbase + ci * 27 + kt * 9 + kh * 3;
        float wv0 = wr[0], wv1 = wr[1], wv2 = wr[2];
        float x0 = xrow[0], x1 = xrow[1], x2 = xrow[2];
        float x3 = xrow[3], x4v = xrow[4], x5 = xrow[5];
        a0 = fmaf(wv0, x0, fmaf(wv1, x1, fmaf(wv2, x2, a0)));
        a1 = fmaf(wv0, x1, fmaf(wv1, x2, fmaf(wv2, x3, a1)));
        a2 = fmaf(wv0, x2, fmaf(wv1, x3, fmaf(wv2, x4v, a2)));
        a3 = fmaf(wv0, x3, fmaf(wv1, x4v, fmaf(wv2, x5, a3)));
      }
    }
  }
  float bias = pb[co];
  size_t off = (size_t)co * NL + t * 256 + h * 16 + w0;
  size_t ibase = (size_t)(gb * 64 + co) * NL + t * 256 + h * 16 + w0;
  s[OX4 + off + 0] = a0 + bias + xin[ibase + 0];
  s[OX4 + off + 1] = a1 + bias + xin[ibase + 1];
  s[OX4 + off + 2] = a2 + bias + xin[ibase + 2];
  s[OX4 + off + 3] = a3 + bias + xin[ibase + 3];
}

// 9. out = 1x1x1 channel mix + norm_b -> fp32 output
__global__ void knorm(const float* __restrict__ nw, const float* __restrict__ nb,
                      float* __restrict__ out, float* __restrict__ ws, int b0) {
  int bi = blockIdx.y, gb = b0 + bi;
  float* s = ws + (size_t)bi * PER_B;
  int idx = blockIdx.x * 256 + threadIdx.x;  // 64*4096
  int co = idx >> 12, p = idx & 4095;
  float acc = nb[co];
  for (int ci = 0; ci < 64; ++ci)
    acc = fmaf(nw[co * 64 + ci], s[OX4 + (size_t)ci * NL + p], acc);
  out[(size_t)(gb * 64 + co) * NL + p] = acc;
}

// ---------------------------------------------------------------------------
extern "C" void kernel_launch(void* const* d_in, const int* in_sizes, int n_in,
                              void* d_out, int out_size, void* d_ws, size_t ws_size,
                              hipStream_t stream) {
  const float* x    = (const float*)d_in[0];
  const float* wip  = (const float*)d_in[1];
  const float* cwf  = (const float*)d_in[2];
  const float* cbf  = (const float*)d_in[3];
  const float* xpf  = (const float*)d_in[4];
  const float* dtwf = (const float*)d_in[5];
  const float* dtbf = (const float*)d_in[6];
  const float* Alf  = (const float*)d_in[7];
  const float* Df   = (const float*)d_in[8];
  const float* cwb  = (const float*)d_in[9];
  const float* cbb  = (const float*)d_in[10];
  const float* xpb  = (const float*)d_in[11];
  const float* dtwb = (const float*)d_in[12];
  const float* dtbb = (const float*)d_in[13];
  const float* Alb  = (const float*)d_in[14];
  const float* Db   = (const float*)d_in[15];
  const float* wout = (const float*)d_in[16];
  const float* pw   = (const float*)d_in[17];
  const float* pb   = (const float*)d_in[18];
  const float* nw   = (const float*)d_in[19];
  const float* nb   = (const float*)d_in[20];

  const size_t PER_B_BYTES = (size_t)PER_B * 4;  // 22,282,240 per batch slab
  int bcnt;
  if (ws_size >= 4 * PER_B_BYTES) bcnt = 4;
  else if (ws_size >= PER_B_BYTES) bcnt = 1;
  else return;
  int passes = 4 / bcnt;

  float* ws = (float*)d_ws;
  for (int p = 0; p < passes; ++p) {
    int b0 = p * bcnt;
    kxz   <<<dim3(4096, bcnt), 256, 0, stream>>>(x, wip, ws, b0);
    kconv <<<dim3(2048, bcnt), 256, 0, stream>>>(cwf, cbf, cwb, cbb, ws);
    kxdbl <<<dim3(640, bcnt), 256, 0, stream>>>(xpf, xpb, ws);
    kdelta<<<dim3(2048, bcnt), 256, 0, stream>>>(dtwf, dtbf, dtwb, dtbb, ws);
    kscanA<<<dim3(4096, bcnt), 64, 0, stream>>>(Alf, Alb, ws);
    kscanB<<<dim3(64, bcnt), 64, 0, stream>>>(ws);
    kscanC<<<dim3(4096, bcnt), 64, 0, stream>>>(Alf, Df, Alb, Db, ws);
    kgate <<<dim3(2048, bcnt), 256, 0, stream>>>(ws);
    kout  <<<dim3(1024, bcnt), 256, 0, stream>>>(wout, ws);
    kconv3<<<dim3(256, bcnt), 256, 0, stream>>>(pw, pb, x, ws, b0);
    knorm <<<dim3(1024, bcnt), 256, 0, stream>>>(nw, nb, (float*)d_out, ws, b0);
  }
}

// Round 9
// 577.615 us; speedup vs baseline: 3.8101x; 1.3676x over previous
//
#include <hip/hip_runtime.h>

// ---------------------------------------------------------------------------
// Bidirectional Mamba block, MI355X. Round 8:
//  - bct: B/C in [l][32] layout (coalesced n-lane reads in scan phases)
//  - P/S chunk-major (coalesced wave transactions in scan phases)
//  - kscanC writes y via LDS staging -> full-line coalesced stores
//  - k2prep fuses dwconv + xproj + delta (LDS-tiled, mirror-tile bwd)
// Shapes: B=4, C=64, D=128, L=4096 (l = h*256 + w*16 + t), N=16, R=8.
// ---------------------------------------------------------------------------

#define NL 4096

__device__ __forceinline__ float siluf_(float x) { return x / (1.f + __expf(-x)); }
__device__ __forceinline__ float softplusf_(float x) {
  return (x > 20.f) ? x : log1pf(__expf(x));
}

// Per-b slab offsets (fp32 elements)
#define OXZ  0u          // xz   [256][4096]
#define OUCF 1048576u    // ucf  [128][4096]
#define OUCB 1572864u    // ucb  [128][4096]  (flipped coords)
#define OXDF 2097152u    // (unused this round)
#define OXDB 2260992u    // (unused this round)
#define ODLF 2424832u    // dlf  [128][4096]
#define ODLB 2949120u    // dlb  [128][4096]  (flipped coords)
#define OYF  3473408u    // yf   [128][4096]
#define OYB  3997696u    // yb   [128][4096]  (flipped coords)
#define OO   4521984u    // scan scratch: P [chunk-major 262144] S [262144];
                         // later o (gated sum) [128][4096]
#define OO2  5046272u    // bct [2][4096][32] until kscanC; then o2 [4096][64]
#define OX4  5308416u    // x4   [64][4096]   conv3d + residual
#define PER_B 5570560u

#define NCH 64   // scan chunks
#define CL  64   // chunk length

// 1. xz[e,l] = sum_c in_proj_w[e,c] * x[b,c,t(l),h(l),w(l)]
__global__ void kxz(const float* __restrict__ x, const float* __restrict__ wip,
                    float* __restrict__ ws, int b0) {
  int bi = blockIdx.y, gb = b0 + bi;
  float* s = ws + (size_t)bi * PER_B;
  int l = blockIdx.x, e = threadIdx.x;
  int t = l & 15, h = l >> 8, w = (l >> 4) & 15;
  size_t xb = (size_t)gb * 64 * NL + t * 256 + h * 16 + w;
  float acc = 0.f;
  for (int c = 0; c < 64; ++c)
    acc = fmaf(wip[e * 64 + c], x[xb + (size_t)c * NL], acc);
  s[OXZ + (size_t)e * NL + l] = acc;
}

// 2. Fused prep per (bi, 32-l tile): dwconv+silu (fwd tile lt; bwd flipped
// tile 127-lt via mirror identity, same X tile), x_dbl = xproj@uc,
// delta = softplus(dtw@dt + dtb), bct (B/C, [l][32]). All writes coalesced.
__global__ __launch_bounds__(256) void k2prep(
    const float* __restrict__ cwf, const float* __restrict__ cbf,
    const float* __restrict__ xpf, const float* __restrict__ dtwf,
    const float* __restrict__ dtbf,
    const float* __restrict__ cwb, const float* __restrict__ cbb,
    const float* __restrict__ xpb, const float* __restrict__ dtwb,
    const float* __restrict__ dtbb,
    float* __restrict__ ws) {
  int bi = blockIdx.y;
  float* s = ws + (size_t)bi * PER_B;
  int lt = blockIdx.x;           // fwd tile index
  int l0 = lt * 32;              // fwd tile start (original coords)
  int l0b = (127 - lt) * 32;     // bwd tile start (flipped coords)
  int tid = threadIdx.x;

  __shared__ float X[128][40];       // j=0..37 <-> xz[l0-3 .. l0+34]
  __shared__ float ucs[2][128][32];
  __shared__ float xds[2][40][33];

  for (int i = tid; i < 128 * 38; i += 256) {
    int d = i / 38, j = i - d * 38;
    int l = l0 - 3 + j;
    X[d][j] = (l >= 0 && l < NL) ? s[OXZ + (size_t)d * NL + l] : 0.f;
  }
  __syncthreads();

  // dwconv + silu.
  // fwd:  uf(li)  = cbf + sum_k cwf[k] * X[d][li+k]            -> l = l0+li
  // bwd:  ub(li') = cbb + sum_k cwb[k] * X[d][37-li'-k]        -> l' = l0b+li'
  for (int i = tid; i < 2 * 128 * 32; i += 256) {
    int br = i >> 12, rem = i & 4095;
    int d = rem >> 5, li = rem & 31;
    float a;
    if (br == 0) {
      a = cbf[d];
#pragma unroll
      for (int k = 0; k < 4; ++k) a = fmaf(cwf[d * 4 + k], X[d][li + k], a);
    } else {
      a = cbb[d];
#pragma unroll
      for (int k = 0; k < 4; ++k) a = fmaf(cwb[d * 4 + k], X[d][37 - li - k], a);
    }
    a = siluf_(a);
    ucs[br][d][li] = a;
    int lg = br ? (l0b + li) : (l0 + li);
    s[(br ? OUCB : OUCF) + (size_t)d * NL + lg] = a;
  }
  __syncthreads();

  // x_dbl[br][e][li] = sum_d xproj[e,d] * ucs[br][d][li]
  for (int j = 0; j < 10; ++j) {
    int out = j * 256 + tid;
    int br = out / 1280;
    int rem = out - br * 1280;
    int e = rem >> 5, li = rem & 31;
    const float* xp = br ? xpb : xpf;
    float acc = 0.f;
    for (int d = 0; d < 128; ++d)
      acc = fmaf(xp[e * 128 + d], ucs[br][d][li], acc);
    xds[br][e][li] = acc;
  }
  __syncthreads();

  // delta
  for (int i = tid; i < 2 * 128 * 32; i += 256) {
    int br = i >> 12, rem = i & 4095;
    int d = rem >> 5, li = rem & 31;
    const float* dtw = br ? dtwb : dtwf;
    float pre = (br ? dtbb : dtbf)[d];
#pragma unroll
    for (int r = 0; r < 8; ++r)
      pre = fmaf(dtw[d * 8 + r], xds[br][r][li], pre);
    int lg = br ? (l0b + li) : (l0 + li);
    s[(br ? ODLB : ODLF) + (size_t)d * NL + lg] = softplusf_(pre);
  }
  // bct[(dir*4096 + l)*32 + k] = xds[dir][8+k][li]  (contiguous runs)
  for (int i = tid; i < 2 * 32 * 32; i += 256) {
    int dir = i >> 10;
    int li = (i >> 5) & 31, k = i & 31;
    int lg = dir ? (l0b + li) : (l0 + li);
    s[OO2 + ((size_t)dir * 4096 + lg) * 32 + k] = xds[dir][8 + k][li];
  }
}

// 5a. Phase A: per-chunk local scan. P = prod(dA), S = chunk scan (h0=0).
// P/S chunk-major: idx = ((chunk*2+dir)*128 + d)*16 + n -> coalesced per wave.
__global__ __launch_bounds__(64) void kscanA(
    const float* __restrict__ Alf, const float* __restrict__ Alb,
    float* __restrict__ ws) {
  int bi = blockIdx.y;
  float* s = ws + (size_t)bi * PER_B;
  int xid = blockIdx.x;
  int chunk = xid >> 6, dir = (xid >> 5) & 1, dblk = xid & 31;
  int n = threadIdx.x & 15, g = threadIdx.x >> 4;
  int d = dblk * 4 + g;
  const float* uc = s + (dir ? OUCB : OUCF) + (size_t)d * NL;
  const float* dl = s + (dir ? ODLB : ODLF) + (size_t)d * NL;
  const float* bct = s + OO2 + (size_t)dir * 4096 * 32;
  float A = -__expf((dir ? Alb : Alf)[d * 16 + n]);
  int l0 = chunk * CL;
  float P = 1.f, S = 0.f;
#pragma unroll 4
  for (int i = 0; i < CL; ++i) {
    int l = l0 + i;
    float dv = dl[l];
    float dA = __expf(dv * A);
    S = fmaf(dA, S, dv * bct[(size_t)l * 32 + n] * uc[l]);
    P *= dA;
  }
  size_t cidx = ((size_t)(chunk * 2 + dir) * 128 + d) * 16 + n;
  s[OO + cidx] = P;
  s[OO + 262144u + cidx] = S;
}

// 5b. Phase B: carry combine. S[c] <- h_in (state at chunk start).
__global__ __launch_bounds__(64) void kscanB(float* __restrict__ ws) {
  int bi = blockIdx.y;
  float* s = ws + (size_t)bi * PER_B;
  int dir = blockIdx.x >> 5, dblk = blockIdx.x & 31;
  int tid = threadIdx.x;
  size_t base = (size_t)dir * 2048 + dblk * 64 + tid;  // ((c*2+dir)*128+d)*16+n
  float carry = 0.f;
#pragma unroll 4
  for (int c = 0; c < NCH; ++c) {
    size_t idx = (size_t)c * 4096 + base;
    float pv = s[OO + idx], sv = s[OO + 262144u + idx];
    s[OO + 262144u + idx] = carry;
    carry = fmaf(pv, carry, sv);
  }
}

// 5c. Phase C: seeded re-scan; y staged in LDS, coalesced full-line stores.
__global__ __launch_bounds__(64) void kscanC(
    const float* __restrict__ Alf, const float* __restrict__ Df,
    const float* __restrict__ Alb, const float* __restrict__ Db,
    float* __restrict__ ws) {
  int bi = blockIdx.y;
  float* s = ws + (size_t)bi * PER_B;
  int xid = blockIdx.x;
  int chunk = xid >> 6, dir = (xid >> 5) & 1, dblk = xid & 31;
  int tid = threadIdx.x;
  int n = tid & 15, g = tid >> 4;
  int d = dblk * 4 + g;
  const float* uc = s + (dir ? OUCB : OUCF) + (size_t)d * NL;
  const float* dl = s + (dir ? ODLB : ODLF) + (size_t)d * NL;
  const float* bct = s + OO2 + (size_t)dir * 4096 * 32;
  float* ybase = s + (dir ? OYB : OYF);
  float A = -__expf((dir ? Alb : Alf)[d * 16 + n]);
  float Dv = (dir ? Db : Df)[d];
  size_t cidx = ((size_t)(chunk * 2 + dir) * 128 + d) * 16 + n;
  float h = s[OO + 262144u + cidx];  // h_in at chunk start
  int l0 = chunk * CL;
  __shared__ float ps[4][CL];
#pragma unroll 2
  for (int i = 0; i < CL; ++i) {
    int l = l0 + i;
    float dv = dl[l], uv = uc[l];
    float dA = __expf(dv * A);
    h = fmaf(dA, h, dv * bct[(size_t)l * 32 + n] * uv);
    float p = h * bct[(size_t)l * 32 + 16 + n];
    p += __shfl_xor(p, 1, 16);
    p += __shfl_xor(p, 2, 16);
    p += __shfl_xor(p, 4, 16);
    p += __shfl_xor(p, 8, 16);
    if (n == 0) ps[g][i] = fmaf(uv, Dv, p);
  }
#pragma unroll
  for (int dd = 0; dd < 4; ++dd)
    ybase[(size_t)(dblk * 4 + dd) * NL + l0 + tid] = ps[dd][tid];
}

// 6. o[d,l] = (yf[d,l] + yb[d,L-1-l]) * silu(z[l])
__global__ void kgate(float* __restrict__ ws) {
  int bi = blockIdx.y;
  float* s = ws + (size_t)bi * PER_B;
  int idx = blockIdx.x * 256 + threadIdx.x;  // 128*4096
  int d = idx >> 12, l = idx & 4095;
  float gz = siluf_(s[OXZ + (size_t)(128 + d) * NL + l]);
  float v = s[OYF + (size_t)d * NL + l] + s[OYB + (size_t)d * NL + (NL - 1 - l)];
  s[OO + (size_t)d * NL + l] = v * gz;
}

// 7. o2[l,c] = sum_d out_proj_w[c,d] * o[d,l]   (o2 bytes == x_recon NCDHW)
__global__ void kout(const float* __restrict__ wout, float* __restrict__ ws) {
  int bi = blockIdx.y;
  float* s = ws + (size_t)bi * PER_B;
  int idx = blockIdx.x * 256 + threadIdx.x;  // 4096*64
  int l = idx >> 6, c = idx & 63;
  float acc = 0.f;
  for (int d = 0; d < 128; ++d)
    acc = fmaf(wout[c * 128 + d], s[OO + (size_t)d * NL + l], acc);
  s[OO2 + (size_t)l * 64 + c] = acc;
}

// 8. x4 = conv3d(x_recon, proj_w, pad=1) + proj_b + residual x. LDS-tiled.
__global__ __launch_bounds__(256) void kconv3(
    const float* __restrict__ pw, const float* __restrict__ pb,
    const float* __restrict__ xin, float* __restrict__ ws, int b0) {
  int bi = blockIdx.y, gb = b0 + bi;
  float* s = ws + (size_t)bi * PER_B;
  int t = blockIdx.x >> 4, h = blockIdx.x & 15;
  int tid = threadIdx.x;
  const float* xr = s + OO2;  // (L,C) bytes == (C,T,H,W)
  __shared__ float Xs[64][3][3][18];
  for (int i = tid; i < 64 * 162; i += 256) {
    int ci = i / 162;
    int rem = i - ci * 162;
    int tt = rem / 54;
    int rem2 = rem - tt * 54;
    int hh = rem2 / 18;
    int ww = rem2 - hh * 18;
    int ts = t + tt - 1, hs = h + hh - 1, wv = ww - 1;
    float v = 0.f;
    if (ts >= 0 && ts < 16 && hs >= 0 && hs < 16 && wv >= 0 && wv < 16)
      v = xr[(size_t)ci * NL + ts * 256 + hs * 16 + wv];
    Xs[ci][tt][hh][ww] = v;
  }
  __syncthreads();
  int co = tid >> 2, wq = tid & 3;
  int w0 = wq * 4;
  float a0 = 0.f, a1 = 0.f, a2 = 0.f, a3 = 0.f;
  const float* wbase = pw + co * (64 * 27);
  for (int ci = 0; ci < 64; ++ci) {
#pragma unroll
    for (int kt = 0; kt < 3; ++kt) {
#pragma unroll
      for (int kh = 0; kh < 3; ++kh) {
        const float* xrow = &Xs[ci][kt][kh][w0];
        const float* wr = wbase + ci * 27 + kt * 9 + kh * 3;
        float wv0 = wr[0], wv1 = wr[1], wv2 = wr[2];
        float x0 = xrow[0], x1 = xrow[1], x2 = xrow[2];
        float x3 = xrow[3], x4v = xrow[4], x5 = xrow[5];
        a0 = fmaf(wv0, x0, fmaf(wv1, x1, fmaf(wv2, x2, a0)));
        a1 = fmaf(wv0, x1, fmaf(wv1, x2, fmaf(wv2, x3, a1)));
        a2 = fmaf(wv0, x2, fmaf(wv1, x3, fmaf(wv2, x4v, a2)));
        a3 = fmaf(wv0, x3, fmaf(wv1, x4v, fmaf(wv2, x5, a3)));
      }
    }
  }
  float bias = pb[co];
  size_t off = (size_t)co * NL + t * 256 + h * 16 + w0;
  size_t ibase = (size_t)(gb * 64 + co) * NL + t * 256 + h * 16 + w0;
  s[OX4 + off + 0] = a0 + bias + xin[ibase + 0];
  s[OX4 + off + 1] = a1 + bias + xin[ibase + 1];
  s[OX4 + off + 2] = a2 + bias + xin[ibase + 2];
  s[OX4 + off + 3] = a3 + bias + xin[ibase + 3];
}

// 9. out = 1x1x1 channel mix + norm_b -> fp32 output
__global__ void knorm(const float* __restrict__ nw, const float* __restrict__ nb,
                      float* __restrict__ out, float* __restrict__ ws, int b0) {
  int bi = blockIdx.y, gb = b0 + bi;
  float* s = ws + (size_t)bi * PER_B;
  int idx = blockIdx.x * 256 + threadIdx.x;  // 64*4096
  int co = idx >> 12, p = idx & 4095;
  float acc = nb[co];
  for (int ci = 0; ci < 64; ++ci)
    acc = fmaf(nw[co * 64 + ci], s[OX4 + (size_t)ci * NL + p], acc);
  out[(size_t)(gb * 64 + co) * NL + p] = acc;
}

// ---------------------------------------------------------------------------
extern "C" void kernel_launch(void* const* d_in, const int* in_sizes, int n_in,
                              void* d_out, int out_size, void* d_ws, size_t ws_size,
                              hipStream_t stream) {
  const float* x    = (const float*)d_in[0];
  const float* wip  = (const float*)d_in[1];
  const float* cwf  = (const float*)d_in[2];
  const float* cbf  = (const float*)d_in[3];
  const float* xpf  = (const float*)d_in[4];
  const float* dtwf = (const float*)d_in[5];
  const float* dtbf = (const float*)d_in[6];
  const float* Alf  = (const float*)d_in[7];
  const float* Df   = (const float*)d_in[8];
  const float* cwb  = (const float*)d_in[9];
  const float* cbb  = (const float*)d_in[10];
  const float* xpb  = (const float*)d_in[11];
  const float* dtwb = (const float*)d_in[12];
  const float* dtbb = (const float*)d_in[13];
  const float* Alb  = (const float*)d_in[14];
  const float* Db   = (const float*)d_in[15];
  const float* wout = (const float*)d_in[16];
  const float* pw   = (const float*)d_in[17];
  const float* pb   = (const float*)d_in[18];
  const float* nw   = (const float*)d_in[19];
  const float* nb   = (const float*)d_in[20];

  const size_t PER_B_BYTES = (size_t)PER_B * 4;  // 22,282,240 per batch slab
  int bcnt;
  if (ws_size >= 4 * PER_B_BYTES) bcnt = 4;
  else if (ws_size >= PER_B_BYTES) bcnt = 1;
  else return;
  int passes = 4 / bcnt;

  float* ws = (float*)d_ws;
  for (int p = 0; p < passes; ++p) {
    int b0 = p * bcnt;
    kxz   <<<dim3(4096, bcnt), 256, 0, stream>>>(x, wip, ws, b0);
    k2prep<<<dim3(128, bcnt), 256, 0, stream>>>(cwf, cbf, xpf, dtwf, dtbf,
                                                cwb, cbb, xpb, dtwb, dtbb, ws);
    kscanA<<<dim3(4096, bcnt), 64, 0, stream>>>(Alf, Alb, ws);
    kscanB<<<dim3(64, bcnt), 64, 0, stream>>>(ws);
    kscanC<<<dim3(4096, bcnt), 64, 0, stream>>>(Alf, Df, Alb, Db, ws);
    kgate <<<dim3(2048, bcnt), 256, 0, stream>>>(ws);
    kout  <<<dim3(1024, bcnt), 256, 0, stream>>>(wout, ws);
    kconv3<<<dim3(256, bcnt), 256, 0, stream>>>(pw, pb, x, ws, b0);
    knorm <<<dim3(1024, bcnt), 256, 0, stream>>>(nw, nb, (float*)d_out, ws, b0);
  }
}

// Round 10
// 475.793 us; speedup vs baseline: 4.6254x; 1.2140x over previous
//
#include <hip/hip_runtime.h>

// ---------------------------------------------------------------------------
// Bidirectional Mamba block, MI355X. Round 9: kxz rewrite (write-coalesced).
// R8's kxz: lane-stride-NL stores -> 128MB WRITE_SIZE (8x amplification),
// 132us. New kxz: block=(bi,h,w), LDS 64c x 16t tile, thread=e writes 16
// consecutive floats (one full line) as float4s. Everything else = R8.
// Shapes: B=4, C=64, D=128, L=4096 (l = h*256 + w*16 + t), N=16, R=8.
// ---------------------------------------------------------------------------

#define NL 4096

__device__ __forceinline__ float siluf_(float x) { return x / (1.f + __expf(-x)); }
__device__ __forceinline__ float softplusf_(float x) {
  return (x > 20.f) ? x : log1pf(__expf(x));
}

// Per-b slab offsets (fp32 elements)
#define OXZ  0u          // xz   [256][4096]
#define OUCF 1048576u    // ucf  [128][4096]
#define OUCB 1572864u    // ucb  [128][4096]  (flipped coords)
#define ODLF 2424832u    // dlf  [128][4096]
#define ODLB 2949120u    // dlb  [128][4096]  (flipped coords)
#define OYF  3473408u    // yf   [128][4096]
#define OYB  3997696u    // yb   [128][4096]  (flipped coords)
#define OO   4521984u    // scan scratch: P [262144] S [262144]; later o [128][4096]
#define OO2  5046272u    // bct [2][4096][32] until kscanC; then o2 [4096][64]
#define OX4  5308416u    // x4   [64][4096]   conv3d + residual
#define PER_B 5570560u

#define NCH 64   // scan chunks
#define CL  64   // chunk length

// 1. xz[e,l] = sum_c in_proj_w[e,c] * seq[c,l].  Block=(bi,h,w): LDS stages
// the 64c x 16t column; thread e accumulates 16 t's and stores one full
// 64-byte line (float4 x4). Grid (256, bcnt).
__global__ __launch_bounds__(256) void kxz(
    const float* __restrict__ x, const float* __restrict__ wip,
    float* __restrict__ ws, int b0) {
  int bi = blockIdx.y, gb = b0 + bi;
  float* s = ws + (size_t)bi * PER_B;
  int bid = blockIdx.x;
  int h = bid >> 4, w = bid & 15;
  int tid = threadIdx.x;
  __shared__ float xs[64][16];
  for (int i = tid; i < 1024; i += 256) {
    int c = i >> 4, t = i & 15;
    xs[c][t] = x[(size_t)(gb * 64 + c) * NL + t * 256 + h * 16 + w];
  }
  __syncthreads();
  int e = tid;
  float acc[16];
#pragma unroll
  for (int t = 0; t < 16; ++t) acc[t] = 0.f;
  for (int c = 0; c < 64; ++c) {
    float wv = wip[e * 64 + c];
#pragma unroll
    for (int t = 0; t < 16; ++t) acc[t] = fmaf(wv, xs[c][t], acc[t]);
  }
  float4* dst = (float4*)(s + OXZ + (size_t)e * NL + h * 256 + w * 16);
#pragma unroll
  for (int q = 0; q < 4; ++q)
    dst[q] = make_float4(acc[q * 4], acc[q * 4 + 1], acc[q * 4 + 2], acc[q * 4 + 3]);
}

// 2. Fused prep per (bi, 32-l tile): dwconv+silu (fwd tile lt; bwd flipped
// tile 127-lt via mirror identity, same X tile), x_dbl = xproj@uc,
// delta = softplus(dtw@dt + dtb), bct (B/C, [l][32]). All writes coalesced.
__global__ __launch_bounds__(256) void k2prep(
    const float* __restrict__ cwf, const float* __restrict__ cbf,
    const float* __restrict__ xpf, const float* __restrict__ dtwf,
    const float* __restrict__ dtbf,
    const float* __restrict__ cwb, const float* __restrict__ cbb,
    const float* __restrict__ xpb, const float* __restrict__ dtwb,
    const float* __restrict__ dtbb,
    float* __restrict__ ws) {
  int bi = blockIdx.y;
  float* s = ws + (size_t)bi * PER_B;
  int lt = blockIdx.x;           // fwd tile index
  int l0 = lt * 32;              // fwd tile start (original coords)
  int l0b = (127 - lt) * 32;     // bwd tile start (flipped coords)
  int tid = threadIdx.x;

  __shared__ float X[128][40];       // j=0..37 <-> xz[l0-3 .. l0+34]
  __shared__ float ucs[2][128][32];
  __shared__ float xds[2][40][33];

  for (int i = tid; i < 128 * 38; i += 256) {
    int d = i / 38, j = i - d * 38;
    int l = l0 - 3 + j;
    X[d][j] = (l >= 0 && l < NL) ? s[OXZ + (size_t)d * NL + l] : 0.f;
  }
  __syncthreads();

  // dwconv + silu.
  // fwd:  uf(li)  = cbf + sum_k cwf[k] * X[d][li+k]            -> l = l0+li
  // bwd:  ub(li') = cbb + sum_k cwb[k] * X[d][37-li'-k]        -> l' = l0b+li'
  for (int i = tid; i < 2 * 128 * 32; i += 256) {
    int br = i >> 12, rem = i & 4095;
    int d = rem >> 5, li = rem & 31;
    float a;
    if (br == 0) {
      a = cbf[d];
#pragma unroll
      for (int k = 0; k < 4; ++k) a = fmaf(cwf[d * 4 + k], X[d][li + k], a);
    } else {
      a = cbb[d];
#pragma unroll
      for (int k = 0; k < 4; ++k) a = fmaf(cwb[d * 4 + k], X[d][37 - li - k], a);
    }
    a = siluf_(a);
    ucs[br][d][li] = a;
    int lg = br ? (l0b + li) : (l0 + li);
    s[(br ? OUCB : OUCF) + (size_t)d * NL + lg] = a;
  }
  __syncthreads();

  // x_dbl[br][e][li] = sum_d xproj[e,d] * ucs[br][d][li]
  for (int j = 0; j < 10; ++j) {
    int out = j * 256 + tid;
    int br = out / 1280;
    int rem = out - br * 1280;
    int e = rem >> 5, li = rem & 31;
    const float* xp = br ? xpb : xpf;
    float acc = 0.f;
    for (int d = 0; d < 128; ++d)
      acc = fmaf(xp[e * 128 + d], ucs[br][d][li], acc);
    xds[br][e][li] = acc;
  }
  __syncthreads();

  // delta
  for (int i = tid; i < 2 * 128 * 32; i += 256) {
    int br = i >> 12, rem = i & 4095;
    int d = rem >> 5, li = rem & 31;
    const float* dtw = br ? dtwb : dtwf;
    float pre = (br ? dtbb : dtbf)[d];
#pragma unroll
    for (int r = 0; r < 8; ++r)
      pre = fmaf(dtw[d * 8 + r], xds[br][r][li], pre);
    int lg = br ? (l0b + li) : (l0 + li);
    s[(br ? ODLB : ODLF) + (size_t)d * NL + lg] = softplusf_(pre);
  }
  // bct[(dir*4096 + l)*32 + k] = xds[dir][8+k][li]  (contiguous runs)
  for (int i = tid; i < 2 * 32 * 32; i += 256) {
    int dir = i >> 10;
    int li = (i >> 5) & 31, k = i & 31;
    int lg = dir ? (l0b + li) : (l0 + li);
    s[OO2 + ((size_t)dir * 4096 + lg) * 32 + k] = xds[dir][8 + k][li];
  }
}

// 5a. Phase A: per-chunk local scan. P = prod(dA), S = chunk scan (h0=0).
// P/S chunk-major: idx = ((chunk*2+dir)*128 + d)*16 + n -> coalesced per wave.
__global__ __launch_bounds__(64) void kscanA(
    const float* __restrict__ Alf, const float* __restrict__ Alb,
    float* __restrict__ ws) {
  int bi = blockIdx.y;
  float* s = ws + (size_t)bi * PER_B;
  int xid = blockIdx.x;
  int chunk = xid >> 6, dir = (xid >> 5) & 1, dblk = xid & 31;
  int n = threadIdx.x & 15, g = threadIdx.x >> 4;
  int d = dblk * 4 + g;
  const float* uc = s + (dir ? OUCB : OUCF) + (size_t)d * NL;
  const float* dl = s + (dir ? ODLB : ODLF) + (size_t)d * NL;
  const float* bct = s + OO2 + (size_t)dir * 4096 * 32;
  float A = -__expf((dir ? Alb : Alf)[d * 16 + n]);
  int l0 = chunk * CL;
  float P = 1.f, S = 0.f;
#pragma unroll 4
  for (int i = 0; i < CL; ++i) {
    int l = l0 + i;
    float dv = dl[l];
    float dA = __expf(dv * A);
    S = fmaf(dA, S, dv * bct[(size_t)l * 32 + n] * uc[l]);
    P *= dA;
  }
  size_t cidx = ((size_t)(chunk * 2 + dir) * 128 + d) * 16 + n;
  s[OO + cidx] = P;
  s[OO + 262144u + cidx] = S;
}

// 5b. Phase B: carry combine. S[c] <- h_in (state at chunk start).
__global__ __launch_bounds__(64) void kscanB(float* __restrict__ ws) {
  int bi = blockIdx.y;
  float* s = ws + (size_t)bi * PER_B;
  int dir = blockIdx.x >> 5, dblk = blockIdx.x & 31;
  int tid = threadIdx.x;
  size_t base = (size_t)dir * 2048 + dblk * 64 + tid;  // ((c*2+dir)*128+d)*16+n
  float carry = 0.f;
#pragma unroll 4
  for (int c = 0; c < NCH; ++c) {
    size_t idx = (size_t)c * 4096 + base;
    float pv = s[OO + idx], sv = s[OO + 262144u + idx];
    s[OO + 262144u + idx] = carry;
    carry = fmaf(pv, carry, sv);
  }
}

// 5c. Phase C: seeded re-scan; y staged in LDS, coalesced full-line stores.
__global__ __launch_bounds__(64) void kscanC(
    const float* __restrict__ Alf, const float* __restrict__ Df,
    const float* __restrict__ Alb, const float* __restrict__ Db,
    float* __restrict__ ws) {
  int bi = blockIdx.y;
  float* s = ws + (size_t)bi * PER_B;
  int xid = blockIdx.x;
  int chunk = xid >> 6, dir = (xid >> 5) & 1, dblk = xid & 31;
  int tid = threadIdx.x;
  int n = tid & 15, g = tid >> 4;
  int d = dblk * 4 + g;
  const float* uc = s + (dir ? OUCB : OUCF) + (size_t)d * NL;
  const float* dl = s + (dir ? ODLB : ODLF) + (size_t)d * NL;
  const float* bct = s + OO2 + (size_t)dir * 4096 * 32;
  float* ybase = s + (dir ? OYB : OYF);
  float A = -__expf((dir ? Alb : Alf)[d * 16 + n]);
  float Dv = (dir ? Db : Df)[d];
  size_t cidx = ((size_t)(chunk * 2 + dir) * 128 + d) * 16 + n;
  float h = s[OO + 262144u + cidx];  // h_in at chunk start
  int l0 = chunk * CL;
  __shared__ float ps[4][CL];
#pragma unroll 2
  for (int i = 0; i < CL; ++i) {
    int l = l0 + i;
    float dv = dl[l], uv = uc[l];
    float dA = __expf(dv * A);
    h = fmaf(dA, h, dv * bct[(size_t)l * 32 + n] * uv);
    float p = h * bct[(size_t)l * 32 + 16 + n];
    p += __shfl_xor(p, 1, 16);
    p += __shfl_xor(p, 2, 16);
    p += __shfl_xor(p, 4, 16);
    p += __shfl_xor(p, 8, 16);
    if (n == 0) ps[g][i] = fmaf(uv, Dv, p);
  }
#pragma unroll
  for (int dd = 0; dd < 4; ++dd)
    ybase[(size_t)(dblk * 4 + dd) * NL + l0 + tid] = ps[dd][tid];
}

// 6. o[d,l] = (yf[d,l] + yb[d,L-1-l]) * silu(z[l])
__global__ void kgate(float* __restrict__ ws) {
  int bi = blockIdx.y;
  float* s = ws + (size_t)bi * PER_B;
  int idx = blockIdx.x * 256 + threadIdx.x;  // 128*4096
  int d = idx >> 12, l = idx & 4095;
  float gz = siluf_(s[OXZ + (size_t)(128 + d) * NL + l]);
  float v = s[OYF + (size_t)d * NL + l] + s[OYB + (size_t)d * NL + (NL - 1 - l)];
  s[OO + (size_t)d * NL + l] = v * gz;
}

// 7. o2[l,c] = sum_d out_proj_w[c,d] * o[d,l]   (o2 bytes == x_recon NCDHW)
__global__ void kout(const float* __restrict__ wout, float* __restrict__ ws) {
  int bi = blockIdx.y;
  float* s = ws + (size_t)bi * PER_B;
  int idx = blockIdx.x * 256 + threadIdx.x;  // 4096*64
  int l = idx >> 6, c = idx & 63;
  float acc = 0.f;
  for (int d = 0; d < 128; ++d)
    acc = fmaf(wout[c * 128 + d], s[OO + (size_t)d * NL + l], acc);
  s[OO2 + (size_t)l * 64 + c] = acc;
}

// 8. x4 = conv3d(x_recon, proj_w, pad=1) + proj_b + residual x. LDS-tiled.
__global__ __launch_bounds__(256) void kconv3(
    const float* __restrict__ pw, const float* __restrict__ pb,
    const float* __restrict__ xin, float* __restrict__ ws, int b0) {
  int bi = blockIdx.y, gb = b0 + bi;
  float* s = ws + (size_t)bi * PER_B;
  int t = blockIdx.x >> 4, h = blockIdx.x & 15;
  int tid = threadIdx.x;
  const float* xr = s + OO2;  // (L,C) bytes == (C,T,H,W)
  __shared__ float Xs[64][3][3][18];
  for (int i = tid; i < 64 * 162; i += 256) {
    int ci = i / 162;
    int rem = i - ci * 162;
    int tt = rem / 54;
    int rem2 = rem - tt * 54;
    int hh = rem2 / 18;
    int ww = rem2 - hh * 18;
    int ts = t + tt - 1, hs = h + hh - 1, wv = ww - 1;
    float v = 0.f;
    if (ts >= 0 && ts < 16 && hs >= 0 && hs < 16 && wv >= 0 && wv < 16)
      v = xr[(size_t)ci * NL + ts * 256 + hs * 16 + wv];
    Xs[ci][tt][hh][ww] = v;
  }
  __syncthreads();
  int co = tid >> 2, wq = tid & 3;
  int w0 = wq * 4;
  float a0 = 0.f, a1 = 0.f, a2 = 0.f, a3 = 0.f;
  const float* wbase = pw + co * (64 * 27);
  for (int ci = 0; ci < 64; ++ci) {
#pragma unroll
    for (int kt = 0; kt < 3; ++kt) {
#pragma unroll
      for (int kh = 0; kh < 3; ++kh) {
        const float* xrow = &Xs[ci][kt][kh][w0];
        const float* wr = wbase + ci * 27 + kt * 9 + kh * 3;
        float wv0 = wr[0], wv1 = wr[1], wv2 = wr[2];
        float x0 = xrow[0], x1 = xrow[1], x2 = xrow[2];
        float x3 = xrow[3], x4v = xrow[4], x5 = xrow[5];
        a0 = fmaf(wv0, x0, fmaf(wv1, x1, fmaf(wv2, x2, a0)));
        a1 = fmaf(wv0, x1, fmaf(wv1, x2, fmaf(wv2, x3, a1)));
        a2 = fmaf(wv0, x2, fmaf(wv1, x3, fmaf(wv2, x4v, a2)));
        a3 = fmaf(wv0, x3, fmaf(wv1, x4v, fmaf(wv2, x5, a3)));
      }
    }
  }
  float bias = pb[co];
  size_t off = (size_t)co * NL + t * 256 + h * 16 + w0;
  size_t ibase = (size_t)(gb * 64 + co) * NL + t * 256 + h * 16 + w0;
  s[OX4 + off + 0] = a0 + bias + xin[ibase + 0];
  s[OX4 + off + 1] = a1 + bias + xin[ibase + 1];
  s[OX4 + off + 2] = a2 + bias + xin[ibase + 2];
  s[OX4 + off + 3] = a3 + bias + xin[ibase + 3];
}

// 9. out = 1x1x1 channel mix + norm_b -> fp32 output
__global__ void knorm(const float* __restrict__ nw, const float* __restrict__ nb,
                      float* __restrict__ out, float* __restrict__ ws, int b0) {
  int bi = blockIdx.y, gb = b0 + bi;
  float* s = ws + (size_t)bi * PER_B;
  int idx = blockIdx.x * 256 + threadIdx.x;  // 64*4096
  int co = idx >> 12, p = idx & 4095;
  float acc = nb[co];
  for (int ci = 0; ci < 64; ++ci)
    acc = fmaf(nw[co * 64 + ci], s[OX4 + (size_t)ci * NL + p], acc);
  out[(size_t)(gb * 64 + co) * NL + p] = acc;
}

// ---------------------------------------------------------------------------
extern "C" void kernel_launch(void* const* d_in, const int* in_sizes, int n_in,
                              void* d_out, int out_size, void* d_ws, size_t ws_size,
                              hipStream_t stream) {
  const float* x    = (const float*)d_in[0];
  const float* wip  = (const float*)d_in[1];
  const float* cwf  = (const float*)d_in[2];
  const float* cbf  = (const float*)d_in[3];
  const float* xpf  = (const float*)d_in[4];
  const float* dtwf = (const float*)d_in[5];
  const float* dtbf = (const float*)d_in[6];
  const float* Alf  = (const float*)d_in[7];
  const float* Df   = (const float*)d_in[8];
  const float* cwb  = (const float*)d_in[9];
  const float* cbb  = (const float*)d_in[10];
  const float* xpb  = (const float*)d_in[11];
  const float* dtwb = (const float*)d_in[12];
  const float* dtbb = (const float*)d_in[13];
  const float* Alb  = (const float*)d_in[14];
  const float* Db   = (const float*)d_in[15];
  const float* wout = (const float*)d_in[16];
  const float* pw   = (const float*)d_in[17];
  const float* pb   = (const float*)d_in[18];
  const float* nw   = (const float*)d_in[19];
  const float* nb   = (const float*)d_in[20];

  const size_t PER_B_BYTES = (size_t)PER_B * 4;  // 22,282,240 per batch slab
  int bcnt;
  if (ws_size >= 4 * PER_B_BYTES) bcnt = 4;
  else if (ws_size >= PER_B_BYTES) bcnt = 1;
  else return;
  int passes = 4 / bcnt;

  float* ws = (float*)d_ws;
  for (int p = 0; p < passes; ++p) {
    int b0 = p * bcnt;
    kxz   <<<dim3(256, bcnt), 256, 0, stream>>>(x, wip, ws, b0);
    k2prep<<<dim3(128, bcnt), 256, 0, stream>>>(cwf, cbf, xpf, dtwf, dtbf,
                                                cwb, cbb, xpb, dtwb, dtbb, ws);
    kscanA<<<dim3(4096, bcnt), 64, 0, stream>>>(Alf, Alb, ws);
    kscanB<<<dim3(64, bcnt), 64, 0, stream>>>(ws);
    kscanC<<<dim3(4096, bcnt), 64, 0, stream>>>(Alf, Df, Alb, Db, ws);
    kgate <<<dim3(2048, bcnt), 256, 0, stream>>>(ws);
    kout  <<<dim3(1024, bcnt), 256, 0, stream>>>(wout, ws);
    kconv3<<<dim3(256, bcnt), 256, 0, stream>>>(pw, pb, x, ws, b0);
    knorm <<<dim3(1024, bcnt), 256, 0, stream>>>(nw, nb, (float*)d_out, ws, b0);
  }
}